// Round 12
// baseline (676.988 us; speedup 1.0000x reference)
//
#include <hip/hip_runtime.h>
#include <hip/hip_fp16.h>

#define ELL_CAP 64   // max degree slots per node; P(Poisson(16) >= 64) ~ 1e-18
#define NSLICE 8     // dst slices, mapped to XCDs via blockIdx & 7
#define EPB 2048     // edges scanned per block (256 threads x 8)

// ---------- preprocessing ----------

// XCD-affinity ELL build, single dispatch. Block b: dst slice (b&7), edge
// chunk (b>>3). Each dst slice's deg/ell lines are written by ONE XCD ->
// atomics stay L2-local. ONE atomic/edge counts degree AND allocates slot.
__global__ __launch_bounds__(256) void ell_fill(
    const int* __restrict__ edges, int* __restrict__ deg,
    int* __restrict__ ell, int e, int n, int slice_sz) {
    int slice = blockIdx.x & (NSLICE - 1);
    int chunk = blockIdx.x >> 3;
    int lo = slice * slice_sz;
    int hi = min(n, lo + slice_sz);
    int base = chunk * EPB + threadIdx.x;
#pragma unroll
    for (int k = 0; k < EPB / 256; ++k) {
        int i = base + k * 256;
        if (i >= e) break;
        int d = __builtin_nontemporal_load(&edges[e + i]);
        if (d < lo || d >= hi) continue;
        int s = __builtin_nontemporal_load(&edges[i]);
        int slot = atomicAdd(&deg[d], 1);
        if (slot < ELL_CAP) ell[((size_t)d << 6) + slot] = s;
    }
}

// per-node constants + ELL row padding to a multiple of 8 with dummy node n.
// Dummy node's g-row is zero, so padded gathers add 0 (one hot line).
__global__ void nodeconst_kernel(const int* __restrict__ deg, float* __restrict__ rs,
                                 float* __restrict__ sq, float* __restrict__ wdeg,
                                 int* __restrict__ ell, int n) {
    int i = blockIdx.x * blockDim.x + threadIdx.x;
    if (i > n) return;  // includes phantom node n (deg 0)
    int v = (i < n) ? deg[i] : 0;
    float d = (float)max(v, 1);
    float r = rsqrtf(d);
    rs[i] = r;
    sq[i] = sqrtf(d);
    wdeg[i] = 0.9f * r * r;
    if (i < n) {
        int dg = min(v, ELL_CAP);
        int dgp = (dg + 7) & ~7;
        for (int k = dg; k < dgp; ++k) ell[((size_t)i << 6) + k] = n;  // dummy
    }
}

// g layout: TWO PLANES of 16 feats. plane p, node i, feat f (f<16):
// halfs index = p*ps16 + i*16 + f, where ps16 = (n+1)*16.
// Row-in-plane = 32 B -> per-plane buffer 3.2 MB, fits 4 MiB per-XCD L2.

// g = rs (.) x, fp32 -> fp16, plane-split. One thread per half2 pair.
__global__ void prescale_kernel(const float2* __restrict__ x2, const float* __restrict__ rs,
                                __half2* __restrict__ g, int n) {
    int i = blockIdx.x * blockDim.x + threadIdx.x;  // pair index
    int node = i >> 4;
    if (node > n) return;
    int j = i & 15;  // pair within node (feats 2j, 2j+1)
    int plane = j >> 3;
    size_t ps8 = (size_t)(n + 1) * 8;  // plane stride in half2 units
    size_t a = (size_t)plane * ps8 + (size_t)node * 8 + (j & 7);
    if (node == n) { g[a] = __floats2half2_rn(0.f, 0.f); return; }
    float2 v = x2[i];
    float r = rs[node];
    g[a] = __floats2half2_rn(v.x * r, v.y * r);
}

// ---------- g-space conv (fp16 plane rows, fp32 accum, padded ELL) ----------
// g_out[d] = wdeg[d] * sum_{s in N(d)} g[s] + 0.1 * g0[d]
// ONE dispatch covers both planes: half = blockIdx & 1 -> with round-robin
// block->XCD mapping, each XCD gathers from ONE 3.2 MB plane (L2-resident).
// Within a half: 8 lanes per node, lane owns 4 B (2 halfs; 8 lanes = 32B row).
// 8-edge rounds: lane q loads ell[j0+q] (coalesced), broadcast via
// __shfl(width=8); 8 independent 4B gathers in flight; next round prefetched.

__global__ __launch_bounds__(256) void conv_kernel(
    const unsigned* __restrict__ gin, const unsigned* __restrict__ g0,
    unsigned* __restrict__ gout, const int* __restrict__ deg,
    const int* __restrict__ ell, const float* __restrict__ wdeg, int n) {
    int half = blockIdx.x & 1;
    int lid = (blockIdx.x >> 1) * blockDim.x + threadIdx.x;
    int node = lid >> 3;
    int q = lid & 7;
    if (node > n) return;  // phantom node n: trips 0 -> writes 0.1*g0 = 0
    size_t ps = (size_t)(n + 1) * 8;  // plane stride in uint units
    const unsigned* gp = gin + (size_t)half * ps;
    int dg = (node < n) ? min(deg[node], ELL_CAP) : 0;
    int trips = (dg + 7) >> 3;  // rounds of 8 edges (ELL padded to x8)
    int j0 = node << 6;
    float w = wdeg[node];
    size_t oidx = (size_t)half * ps + ((size_t)node << 3) + q;
    union UH { unsigned u; __half2 h; };
    UH g0v;
    g0v.u = g0[oidx];  // issued early; latency overlaps the loop
    float2 a0 = {0.f, 0.f}, a1 = {0.f, 0.f}, a2 = {0.f, 0.f}, a3 = {0.f, 0.f};
    int scur = ell[j0 + q];  // unused if trips==0; allocation padded
    for (int r = 0; r < trips; ++r) {
        int snext = ell[j0 + (r + 1) * 8 + q];  // prefetch (padded alloc)
        int s0 = __shfl(scur, 0, 8), s1 = __shfl(scur, 1, 8);
        int s2 = __shfl(scur, 2, 8), s3 = __shfl(scur, 3, 8);
        int s4 = __shfl(scur, 4, 8), s5 = __shfl(scur, 5, 8);
        int s6 = __shfl(scur, 6, 8), s7 = __shfl(scur, 7, 8);
        UH v0, v1, v2, v3, v4, v5, v6, v7;
        v0.u = gp[(size_t)s0 * 8 + q];
        v1.u = gp[(size_t)s1 * 8 + q];
        v2.u = gp[(size_t)s2 * 8 + q];
        v3.u = gp[(size_t)s3 * 8 + q];
        v4.u = gp[(size_t)s4 * 8 + q];
        v5.u = gp[(size_t)s5 * 8 + q];
        v6.u = gp[(size_t)s6 * 8 + q];
        v7.u = gp[(size_t)s7 * 8 + q];
        float2 t;
        t = __half22float2(v0.h); a0.x += t.x; a0.y += t.y;
        t = __half22float2(v1.h); a1.x += t.x; a1.y += t.y;
        t = __half22float2(v2.h); a2.x += t.x; a2.y += t.y;
        t = __half22float2(v3.h); a3.x += t.x; a3.y += t.y;
        t = __half22float2(v4.h); a0.x += t.x; a0.y += t.y;
        t = __half22float2(v5.h); a1.x += t.x; a1.y += t.y;
        t = __half22float2(v6.h); a2.x += t.x; a2.y += t.y;
        t = __half22float2(v7.h); a3.x += t.x; a3.y += t.y;
        scur = snext;
    }
    float2 g0f = __half22float2(g0v.h);
    float rx = w * (a0.x + a1.x + a2.x + a3.x) + 0.1f * g0f.x;
    float ry = w * (a0.y + a1.y + a2.y + a3.y) + 0.1f * g0f.y;
    UH o;
    o.h = __floats2half2_rn(rx, ry);
    gout[oidx] = o.u;
}

// ---------- per-(node,feature) MLP, fused with g->h and h->g conversions ----------
// Plane-aware addressing. Covers phantom node n: writes zero.

__global__ __launch_bounds__(256) void mlp_kernel(
    const __half* __restrict__ gin, __half* __restrict__ gout,
    const float* __restrict__ rs, const float* __restrict__ sq,
    const float* __restrict__ emb,   // [32][6]
    const float* __restrict__ W1,    // [7][9] row-major
    const float* __restrict__ b1,    // [9]
    const float* __restrict__ W2,    // [9]
    const float* __restrict__ b2,    // [1]
    int n) {
    __shared__ float c[32][9];
    __shared__ float w0[9], w2[9];
    __shared__ float b2s;
    int tid = threadIdx.x;
    for (int i = tid; i < 288; i += blockDim.x) {
        int f = i / 9, jj = i % 9;
        float acc = b1[jj];
#pragma unroll
        for (int k = 0; k < 6; ++k) acc += emb[f * 6 + k] * W1[(1 + k) * 9 + jj];
        c[f][jj] = acc;
    }
    if (tid < 9) { w0[tid] = W1[tid]; w2[tid] = W2[tid]; }
    if (tid == 0) b2s = b2[0];
    __syncthreads();
    int gid = blockIdx.x * blockDim.x + tid;
    int node = gid >> 5;
    if (node > n) return;
    int f = gid & 31;
    size_t ps16 = (size_t)(n + 1) * 16;  // plane stride in half units
    size_t a = (size_t)(f >> 4) * ps16 + (size_t)node * 16 + (f & 15);
    if (node == n) { gout[a] = __float2half_rn(0.f); return; }
    float xv = __half2float(gin[a]) * sq[node];
    float acc = b2s;
#pragma unroll
    for (int jj = 0; jj < 9; ++jj)
        acc += fmaxf(xv * w0[jj] + c[f][jj], 0.0f) * w2[jj];
    gout[a] = __float2half_rn(acc * rs[node]);
}

// ---------- output projection (fused g->h): out = (sq .* g) @ Wout + bout ----------

__global__ __launch_bounds__(256) void out_kernel(
    const __half* __restrict__ g, const float* __restrict__ sq,
    const float* __restrict__ Wout, const float* __restrict__ bout,
    float* __restrict__ out, int n) {
    __shared__ float w[32 * 16];
    __shared__ float bo[16];
    int tid = threadIdx.x;
    for (int i = tid; i < 512; i += blockDim.x) w[i] = Wout[i];
    if (tid < 16) bo[tid] = bout[tid];
    __syncthreads();
    int gid = blockIdx.x * blockDim.x + tid;
    int node = gid >> 4;
    int cls = gid & 15;
    if (node >= n) return;
    size_t ps16 = (size_t)(n + 1) * 16;
    const __half* g0p = g + (size_t)node * 16;          // plane 0 row
    const __half* g1p = g + ps16 + (size_t)node * 16;   // plane 1 row
    float acc = 0.0f;
#pragma unroll
    for (int f = 0; f < 16; ++f) acc += __half2float(g0p[f]) * w[f * 16 + cls];
#pragma unroll
    for (int f = 0; f < 16; ++f) acc += __half2float(g1p[f]) * w[(16 + f) * 16 + cls];
    out[gid] = acc * sq[node] + bo[cls];
}

extern "C" void kernel_launch(void* const* d_in, const int* in_sizes, int n_in,
                              void* d_out, int out_size, void* d_ws, size_t ws_size,
                              hipStream_t stream) {
    const float* x    = (const float*)d_in[0];
    const int* edges  = (const int*)d_in[1];
    const float* emb  = (const float*)d_in[2];
    const float* W1   = (const float*)d_in[3];
    const float* b1   = (const float*)d_in[4];
    const float* W2   = (const float*)d_in[5];
    const float* b2   = (const float*)d_in[6];
    const float* Wout = (const float*)d_in[7];
    const float* bout = (const float*)d_in[8];
    float* out        = (float*)d_out;

    const int N = in_sizes[0] / 32;
    const int E = in_sizes[1] / 2;

    size_t off = 0;
    auto walloc = [&](size_t bytes) {
        void* p = (char*)d_ws + off;
        off += (bytes + 255) & ~(size_t)255;
        return p;
    };
    // all per-node arrays sized N+1 for the phantom (dummy) node N
    int*     deg   = (int*)    walloc((size_t)(N + 1) * 4);
    float*   rs    = (float*)  walloc((size_t)(N + 1) * 4);
    float*   sq    = (float*)  walloc((size_t)(N + 1) * 4);
    float*   wdeg  = (float*)  walloc((size_t)(N + 1) * 4);
    int*     ell   = (int*)    walloc((size_t)(N + 1) * ELL_CAP * 4 + 256);
    __half*  g0buf = (__half*) walloc((size_t)(N + 1) * 32 * 2);
    __half*  bufA  = (__half*) walloc((size_t)(N + 1) * 32 * 2);
    __half*  bufB  = (__half*) walloc((size_t)(N + 1) * 32 * 2);

    hipMemsetAsync(deg, 0, (size_t)(N + 1) * 4, stream);
    // XCD-affinity ELL build: one dispatch, dst slice = blockIdx & 7
    {
        int slice_sz = (N + NSLICE - 1) / NSLICE;
        int chunks = (E + EPB - 1) / EPB;
        ell_fill<<<chunks * NSLICE, 256, 0, stream>>>(edges, deg, ell, E, N, slice_sz);
    }
    nodeconst_kernel<<<(N + 1 + 255) / 256, 256, 0, stream>>>(deg, rs, sq, wdeg, ell, N);

    const int blocks_per_half = ((N + 1) * 8 + 255) / 256;
    const int conv_blocks = blocks_per_half * 2;      // half = blockIdx & 1
    const int elem_blocks = ((N + 1) * 32 + 255) / 256;
    const int pair_blocks = ((N + 1) * 16 + 255) / 256;

    prescale_kernel<<<pair_blocks, 256, 0, stream>>>((const float2*)x, rs,
                                                     (__half2*)g0buf, N);

    // diffuse #1 in g-space (g0 = g0buf); 10 iters ends in bufB
    {
        const unsigned* gin = (const unsigned*)g0buf;
        for (int it = 0; it < 10; ++it) {
            unsigned* go = (unsigned*)((it & 1) ? bufB : bufA);
            conv_kernel<<<conv_blocks, 256, 0, stream>>>(gin, (const unsigned*)g0buf, go,
                                                         deg, ell, wdeg, N);
            gin = go;
        }
    }
    // MLP (g->h, mlp, h->g): bufB -> g0buf (becomes g0 of diffuse #2)
    mlp_kernel<<<elem_blocks, 256, 0, stream>>>(bufB, g0buf, rs, sq, emb, W1, b1, W2, b2, N);

    // diffuse #2 in g-space (g0 = g0buf); ends in bufB
    {
        const unsigned* gin = (const unsigned*)g0buf;
        for (int it = 0; it < 10; ++it) {
            unsigned* go = (unsigned*)((it & 1) ? bufB : bufA);
            conv_kernel<<<conv_blocks, 256, 0, stream>>>(gin, (const unsigned*)g0buf, go,
                                                         deg, ell, wdeg, N);
            gin = go;
        }
    }
    // out = (sq .* bufB) @ Wout + bout
    out_kernel<<<(N * 16 + 255) / 256, 256, 0, stream>>>(bufB, sq, Wout, bout, out, N);
}

// Round 14
// 637.903 us; speedup vs baseline: 1.0613x; 1.0613x over previous
//
#include <hip/hip_runtime.h>
#include <hip/hip_fp16.h>

#define ELL_CAP 64   // max degree slots per node; P(Poisson(16) >= 64) ~ 1e-18
#define NSLICE 8     // dst slices, mapped to XCDs via blockIdx & 7
#define EPB 2048     // edges scanned per block (256 threads x 8)

// ---------- preprocessing ----------

// XCD-affinity ELL build, single dispatch. Block b: dst slice (b&7), edge
// chunk (b>>3). Each dst slice's deg/ell lines are written by ONE XCD ->
// atomics stay L2-local. ONE atomic/edge counts degree AND allocates slot.
__global__ __launch_bounds__(256) void ell_fill(
    const int* __restrict__ edges, int* __restrict__ deg,
    int* __restrict__ ell, int e, int n, int slice_sz) {
    int slice = blockIdx.x & (NSLICE - 1);
    int chunk = blockIdx.x >> 3;
    int lo = slice * slice_sz;
    int hi = min(n, lo + slice_sz);
    int base = chunk * EPB + threadIdx.x;
#pragma unroll
    for (int k = 0; k < EPB / 256; ++k) {
        int i = base + k * 256;
        if (i >= e) break;
        int d = __builtin_nontemporal_load(&edges[e + i]);
        if (d < lo || d >= hi) continue;
        int s = __builtin_nontemporal_load(&edges[i]);
        int slot = atomicAdd(&deg[d], 1);
        if (slot < ELL_CAP) ell[((size_t)d << 6) + slot] = s;
    }
}

// per-node constants + ELL row padding to a multiple of 8 with dummy node n.
// Dummy node's g-row is zero, so padded gathers add 0 (one hot line).
__global__ void nodeconst_kernel(const int* __restrict__ deg, float* __restrict__ rs,
                                 float* __restrict__ sq, float* __restrict__ wdeg,
                                 int* __restrict__ ell, int n) {
    int i = blockIdx.x * blockDim.x + threadIdx.x;
    if (i > n) return;  // includes phantom node n (deg 0)
    int v = (i < n) ? deg[i] : 0;
    float d = (float)max(v, 1);
    float r = rsqrtf(d);
    rs[i] = r;
    sq[i] = sqrtf(d);
    wdeg[i] = 0.9f * r * r;
    if (i < n) {
        int dg = min(v, ELL_CAP);
        int dgp = (dg + 7) & ~7;
        for (int k = dg; k < dgp; ++k) ell[((size_t)i << 6) + k] = n;  // dummy
    }
}

// g = rs (.) x, fp32 -> fp16. One thread per feature pair. Covers phantom
// node n (writes zeros; never reads x out of bounds).
__global__ void prescale_kernel(const float2* __restrict__ x2, const float* __restrict__ rs,
                                __half2* __restrict__ g, int n) {
    int i = blockIdx.x * blockDim.x + threadIdx.x;
    int node = i >> 4;
    if (node > n) return;
    if (node == n) { g[i] = __floats2half2_rn(0.f, 0.f); return; }
    float2 v = x2[i];
    float r = rs[node];
    g[i] = __floats2half2_rn(v.x * r, v.y * r);
}

// ---------- g-space conv (fp16 rows, packed-fp16 partial accum, padded ELL) ----
// g_out[d] = wdeg[d] * sum_{s in N(d)} g[s] + 0.1 * g0[d]
// 8 lanes per node, lane owns 4 halfs (8B; 8 lanes = one 64B row = 1 line).
// 8-edge rounds; entries coop-loaded + __shfl(width=8) broadcast; 8 indep
// gathers/round. Accumulation: v_pk_add_f16 into 4 half2-pair chains (16
// pk-adds/round vs 16 cvt + 32 add), flushed to fp32 every 2 rounds (wave-
// uniform r&1) + once after the loop. Max 16 fp16 adds per flush group.

union H4 {
    uint2 u;
    __half2 h[2];
};

__global__ __launch_bounds__(256) void conv_kernel(
    const uint2* __restrict__ gin, const uint2* __restrict__ g0,
    uint2* __restrict__ gout, const int* __restrict__ deg,
    const int* __restrict__ ell, const float* __restrict__ wdeg, int n) {
    int gid = blockIdx.x * blockDim.x + threadIdx.x;
    int node = gid >> 3;
    int q = gid & 7;
    if (node > n) return;  // phantom node n: trips 0 -> writes 0.1*g0 = 0
    int dg = (node < n) ? min(deg[node], ELL_CAP) : 0;
    int trips = (dg + 7) >> 3;  // rounds of 8 edges (ELL padded to x8)
    int j0 = node << 6;
    float w = wdeg[node];
    H4 g0v;
    g0v.u = g0[gid];  // issued early; latency overlaps the loop
    // fp32 master accumulators
    float ax = 0.f, ay = 0.f, az = 0.f, aw = 0.f;
    // fp16 packed partial accumulators: 4 chains x 2 half2 (lo=feats01, hi=feats23)
    __half2 b0l = __floats2half2_rn(0.f, 0.f), b0h = b0l;
    __half2 b1l = b0l, b1h = b0l;
    __half2 b2l = b0l, b2h = b0l;
    __half2 b3l = b0l, b3h = b0l;
    int scur = ell[j0 + q];  // unused if trips==0; allocation padded
    for (int r = 0; r < trips; ++r) {
        int snext = ell[j0 + (r + 1) * 8 + q];  // prefetch (padded alloc)
        int s0 = __shfl(scur, 0, 8), s1 = __shfl(scur, 1, 8);
        int s2 = __shfl(scur, 2, 8), s3 = __shfl(scur, 3, 8);
        int s4 = __shfl(scur, 4, 8), s5 = __shfl(scur, 5, 8);
        int s6 = __shfl(scur, 6, 8), s7 = __shfl(scur, 7, 8);
        H4 v0, v1, v2, v3, v4, v5, v6, v7;
        v0.u = gin[(size_t)s0 * 8 + q];
        v1.u = gin[(size_t)s1 * 8 + q];
        v2.u = gin[(size_t)s2 * 8 + q];
        v3.u = gin[(size_t)s3 * 8 + q];
        v4.u = gin[(size_t)s4 * 8 + q];
        v5.u = gin[(size_t)s5 * 8 + q];
        v6.u = gin[(size_t)s6 * 8 + q];
        v7.u = gin[(size_t)s7 * 8 + q];
        b0l = __hadd2(b0l, v0.h[0]); b0h = __hadd2(b0h, v0.h[1]);
        b1l = __hadd2(b1l, v1.h[0]); b1h = __hadd2(b1h, v1.h[1]);
        b2l = __hadd2(b2l, v2.h[0]); b2h = __hadd2(b2h, v2.h[1]);
        b3l = __hadd2(b3l, v3.h[0]); b3h = __hadd2(b3h, v3.h[1]);
        b0l = __hadd2(b0l, v4.h[0]); b0h = __hadd2(b0h, v4.h[1]);
        b1l = __hadd2(b1l, v5.h[0]); b1h = __hadd2(b1h, v5.h[1]);
        b2l = __hadd2(b2l, v6.h[0]); b2h = __hadd2(b2h, v6.h[1]);
        b3l = __hadd2(b3l, v7.h[0]); b3h = __hadd2(b3h, v7.h[1]);
        if (r & 1) {  // wave-uniform flush every 2 rounds (max 16 fp16 adds)
            float2 t;
            t = __half22float2(b0l); ax += t.x; ay += t.y;
            t = __half22float2(b0h); az += t.x; aw += t.y;
            t = __half22float2(b1l); ax += t.x; ay += t.y;
            t = __half22float2(b1h); az += t.x; aw += t.y;
            t = __half22float2(b2l); ax += t.x; ay += t.y;
            t = __half22float2(b2h); az += t.x; aw += t.y;
            t = __half22float2(b3l); ax += t.x; ay += t.y;
            t = __half22float2(b3h); az += t.x; aw += t.y;
            b0l = __floats2half2_rn(0.f, 0.f); b0h = b0l;
            b1l = b0l; b1h = b0l;
            b2l = b0l; b2h = b0l;
            b3l = b0l; b3h = b0l;
        }
        scur = snext;
    }
    {   // final flush (covers trailing odd round; zeros if already flushed)
        float2 t;
        t = __half22float2(b0l); ax += t.x; ay += t.y;
        t = __half22float2(b0h); az += t.x; aw += t.y;
        t = __half22float2(b1l); ax += t.x; ay += t.y;
        t = __half22float2(b1h); az += t.x; aw += t.y;
        t = __half22float2(b2l); ax += t.x; ay += t.y;
        t = __half22float2(b2h); az += t.x; aw += t.y;
        t = __half22float2(b3l); ax += t.x; ay += t.y;
        t = __half22float2(b3h); az += t.x; aw += t.y;
    }
    float2 g0lo = __half22float2(g0v.h[0]);
    float2 g0hi = __half22float2(g0v.h[1]);
    float rx = w * ax + 0.1f * g0lo.x;
    float ry = w * ay + 0.1f * g0lo.y;
    float rz = w * az + 0.1f * g0hi.x;
    float rw = w * aw + 0.1f * g0hi.y;
    H4 o;
    o.h[0] = __floats2half2_rn(rx, ry);
    o.h[1] = __floats2half2_rn(rz, rw);
    gout[gid] = o.u;
}

// ---------- per-(node,feature) MLP, fused with g->h and h->g conversions ----------
// Covers phantom node n: writes zero (mlp(0) != 0, so explicit).

__global__ __launch_bounds__(256) void mlp_kernel(
    const __half* __restrict__ gin, __half* __restrict__ gout,
    const float* __restrict__ rs, const float* __restrict__ sq,
    const float* __restrict__ emb,   // [32][6]
    const float* __restrict__ W1,    // [7][9] row-major
    const float* __restrict__ b1,    // [9]
    const float* __restrict__ W2,    // [9]
    const float* __restrict__ b2,    // [1]
    int n) {
    __shared__ float c[32][9];
    __shared__ float w0[9], w2[9];
    __shared__ float b2s;
    int tid = threadIdx.x;
    for (int i = tid; i < 288; i += blockDim.x) {
        int f = i / 9, jj = i % 9;
        float acc = b1[jj];
#pragma unroll
        for (int k = 0; k < 6; ++k) acc += emb[f * 6 + k] * W1[(1 + k) * 9 + jj];
        c[f][jj] = acc;
    }
    if (tid < 9) { w0[tid] = W1[tid]; w2[tid] = W2[tid]; }
    if (tid == 0) b2s = b2[0];
    __syncthreads();
    int gid = blockIdx.x * blockDim.x + tid;
    int node = gid >> 5;
    if (node > n) return;
    if (node == n) { gout[gid] = __float2half_rn(0.f); return; }
    int f = gid & 31;
    float xv = __half2float(gin[gid]) * sq[node];
    float acc = b2s;
#pragma unroll
    for (int jj = 0; jj < 9; ++jj)
        acc += fmaxf(xv * w0[jj] + c[f][jj], 0.0f) * w2[jj];
    gout[gid] = __float2half_rn(acc * rs[node]);
}

// ---------- output projection (fused g->h): out = (sq .* g) @ Wout + bout ----------

__global__ __launch_bounds__(256) void out_kernel(
    const __half* __restrict__ g, const float* __restrict__ sq,
    const float* __restrict__ Wout, const float* __restrict__ bout,
    float* __restrict__ out, int n) {
    __shared__ float w[32 * 16];
    __shared__ float bo[16];
    int tid = threadIdx.x;
    for (int i = tid; i < 512; i += blockDim.x) w[i] = Wout[i];
    if (tid < 16) bo[tid] = bout[tid];
    __syncthreads();
    int gid = blockIdx.x * blockDim.x + tid;
    int node = gid >> 4;
    int cls = gid & 15;
    if (node >= n) return;
    const __half* gr = g + (size_t)node * 32;
    float acc = 0.0f;
#pragma unroll
    for (int f = 0; f < 32; ++f) acc += __half2float(gr[f]) * w[f * 16 + cls];
    out[gid] = acc * sq[node] + bo[cls];
}

extern "C" void kernel_launch(void* const* d_in, const int* in_sizes, int n_in,
                              void* d_out, int out_size, void* d_ws, size_t ws_size,
                              hipStream_t stream) {
    const float* x    = (const float*)d_in[0];
    const int* edges  = (const int*)d_in[1];
    const float* emb  = (const float*)d_in[2];
    const float* W1   = (const float*)d_in[3];
    const float* b1   = (const float*)d_in[4];
    const float* W2   = (const float*)d_in[5];
    const float* b2   = (const float*)d_in[6];
    const float* Wout = (const float*)d_in[7];
    const float* bout = (const float*)d_in[8];
    float* out        = (float*)d_out;

    const int N = in_sizes[0] / 32;
    const int E = in_sizes[1] / 2;

    size_t off = 0;
    auto walloc = [&](size_t bytes) {
        void* p = (char*)d_ws + off;
        off += (bytes + 255) & ~(size_t)255;
        return p;
    };
    // all per-node arrays sized N+1 for the phantom (dummy) node N
    int*     deg   = (int*)    walloc((size_t)(N + 1) * 4);
    float*   rs    = (float*)  walloc((size_t)(N + 1) * 4);
    float*   sq    = (float*)  walloc((size_t)(N + 1) * 4);
    float*   wdeg  = (float*)  walloc((size_t)(N + 1) * 4);
    int*     ell   = (int*)    walloc((size_t)(N + 1) * ELL_CAP * 4 + 256);
    __half*  g0buf = (__half*) walloc((size_t)(N + 1) * 32 * 2);
    __half*  bufA  = (__half*) walloc((size_t)(N + 1) * 32 * 2);
    __half*  bufB  = (__half*) walloc((size_t)(N + 1) * 32 * 2);

    hipMemsetAsync(deg, 0, (size_t)(N + 1) * 4, stream);
    // XCD-affinity ELL build: one dispatch, dst slice = blockIdx & 7
    {
        int slice_sz = (N + NSLICE - 1) / NSLICE;
        int chunks = (E + EPB - 1) / EPB;
        ell_fill<<<chunks * NSLICE, 256, 0, stream>>>(edges, deg, ell, E, N, slice_sz);
    }
    nodeconst_kernel<<<(N + 1 + 255) / 256, 256, 0, stream>>>(deg, rs, sq, wdeg, ell, N);

    const int conv_blocks = ((N + 1) * 8 + 255) / 256;
    const int elem_blocks = ((N + 1) * 32 + 255) / 256;
    const int pair_blocks = ((N + 1) * 16 + 255) / 256;

    prescale_kernel<<<pair_blocks, 256, 0, stream>>>((const float2*)x, rs,
                                                     (__half2*)g0buf, N);

    // diffuse #1 in g-space (g0 = g0buf); 10 iters ends in bufB
    {
        const uint2* gin = (const uint2*)g0buf;
        for (int it = 0; it < 10; ++it) {
            uint2* go = (uint2*)((it & 1) ? bufB : bufA);
            conv_kernel<<<conv_blocks, 256, 0, stream>>>(gin, (const uint2*)g0buf, go,
                                                         deg, ell, wdeg, N);
            gin = go;
        }
    }
    // MLP (g->h, mlp, h->g): bufB -> g0buf (becomes g0 of diffuse #2)
    mlp_kernel<<<elem_blocks, 256, 0, stream>>>(bufB, g0buf, rs, sq, emb, W1, b1, W2, b2, N);

    // diffuse #2 in g-space (g0 = g0buf); ends in bufB
    {
        const uint2* gin = (const uint2*)g0buf;
        for (int it = 0; it < 10; ++it) {
            uint2* go = (uint2*)((it & 1) ? bufB : bufA);
            conv_kernel<<<conv_blocks, 256, 0, stream>>>(gin, (const uint2*)g0buf, go,
                                                         deg, ell, wdeg, N);
            gin = go;
        }
    }
    // out = (sq .* bufB) @ Wout + bout
    out_kernel<<<(N * 16 + 255) / 256, 256, 0, stream>>>(bufB, sq, Wout, bout, out, N);
}

// Round 15
// 626.962 us; speedup vs baseline: 1.0798x; 1.0175x over previous
//
#include <hip/hip_runtime.h>
#include <hip/hip_fp16.h>

#define ELL_CAP 64   // max degree slots per node; P(Poisson(16) >= 64) ~ 1e-18
#define NSLICE 8     // dst slices, mapped to XCDs via blockIdx & 7
#define EPB 2048     // edges scanned per block (256 threads x 8)

// ---------- preprocessing ----------

// XCD-affinity ELL build, single dispatch. Block b: dst slice (b&7), edge
// chunk (b>>3). Each dst slice's deg/ell lines are written by ONE XCD ->
// atomics stay L2-local. ONE atomic/edge counts degree AND allocates slot.
// Plain loads (no NT hint): edges (12.8 MB) L3-resident, so the 8x logical
// dst re-read is served by L3, not HBM.
__global__ __launch_bounds__(256) void ell_fill(
    const int* __restrict__ edges, int* __restrict__ deg,
    int* __restrict__ ell, int e, int n, int slice_sz) {
    int slice = blockIdx.x & (NSLICE - 1);
    int chunk = blockIdx.x >> 3;
    int lo = slice * slice_sz;
    int hi = min(n, lo + slice_sz);
    int base = chunk * EPB + threadIdx.x;
#pragma unroll
    for (int k = 0; k < EPB / 256; ++k) {
        int i = base + k * 256;
        if (i >= e) break;
        int d = edges[e + i];
        if (d < lo || d >= hi) continue;
        int s = edges[i];
        int slot = atomicAdd(&deg[d], 1);
        if (slot < ELL_CAP) ell[((size_t)d << 6) + slot] = s;
    }
}

// per-node constants + ELL row padding to a multiple of 8 with dummy node n.
// Dummy node's g-row is zero, so padded gathers add 0 (one hot line).
__global__ void nodeconst_kernel(const int* __restrict__ deg, float* __restrict__ rs,
                                 float* __restrict__ sq, float* __restrict__ wdeg,
                                 int* __restrict__ ell, int n) {
    int i = blockIdx.x * blockDim.x + threadIdx.x;
    if (i > n) return;  // includes phantom node n (deg 0)
    int v = (i < n) ? deg[i] : 0;
    float d = (float)max(v, 1);
    float r = rsqrtf(d);
    rs[i] = r;
    sq[i] = sqrtf(d);
    wdeg[i] = 0.9f * r * r;
    if (i < n) {
        int dg = min(v, ELL_CAP);
        int dgp = (dg + 7) & ~7;
        for (int k = dg; k < dgp; ++k) ell[((size_t)i << 6) + k] = n;  // dummy
    }
}

// g = rs (.) x, fp32 -> fp16. One thread per feature pair. Covers phantom
// node n (writes zeros; never reads x out of bounds).
__global__ void prescale_kernel(const float2* __restrict__ x2, const float* __restrict__ rs,
                                __half2* __restrict__ g, int n) {
    int i = blockIdx.x * blockDim.x + threadIdx.x;
    int node = i >> 4;
    if (node > n) return;
    if (node == n) { g[i] = __floats2half2_rn(0.f, 0.f); return; }
    float2 v = x2[i];
    float r = rs[node];
    g[i] = __floats2half2_rn(v.x * r, v.y * r);
}

// ---------- g-space conv (fp16 rows, packed-fp16 partial accum, padded ELL) ----
// g_out[d] = wdeg[d] * sum_{s in N(d)} g[s] + 0.1 * g0[d]
// 8 lanes per node, lane owns 4 halfs (8B; 8 lanes = one 64B row = 1 line).
// 8-edge rounds; entries coop-loaded + __shfl(width=8) broadcast; 8 indep
// gathers/round. Accumulation: v_pk_add_f16 into 4 half2-pair chains,
// flushed to fp32 every 2 rounds (wave-uniform) + once after the loop.
// At ~25 us/conv this kernel moves ~146 MB => ~5.8 TB/s effective — at the
// empirical random-gather ceiling (6 structural variants all plateau here).

union H4 {
    uint2 u;
    __half2 h[2];
};

__global__ __launch_bounds__(256) void conv_kernel(
    const uint2* __restrict__ gin, const uint2* __restrict__ g0,
    uint2* __restrict__ gout, const int* __restrict__ deg,
    const int* __restrict__ ell, const float* __restrict__ wdeg, int n) {
    int gid = blockIdx.x * blockDim.x + threadIdx.x;
    int node = gid >> 3;
    int q = gid & 7;
    if (node > n) return;  // phantom node n: trips 0 -> writes 0.1*g0 = 0
    int dg = (node < n) ? min(deg[node], ELL_CAP) : 0;
    int trips = (dg + 7) >> 3;  // rounds of 8 edges (ELL padded to x8)
    int j0 = node << 6;
    float w = wdeg[node];
    H4 g0v;
    g0v.u = g0[gid];  // issued early; latency overlaps the loop
    // fp32 master accumulators
    float ax = 0.f, ay = 0.f, az = 0.f, aw = 0.f;
    // fp16 packed partial accumulators: 4 chains x 2 half2 (lo=feats01, hi=feats23)
    __half2 b0l = __floats2half2_rn(0.f, 0.f), b0h = b0l;
    __half2 b1l = b0l, b1h = b0l;
    __half2 b2l = b0l, b2h = b0l;
    __half2 b3l = b0l, b3h = b0l;
    int scur = ell[j0 + q];  // unused if trips==0; allocation padded
    for (int r = 0; r < trips; ++r) {
        int snext = ell[j0 + (r + 1) * 8 + q];  // prefetch (padded alloc)
        int s0 = __shfl(scur, 0, 8), s1 = __shfl(scur, 1, 8);
        int s2 = __shfl(scur, 2, 8), s3 = __shfl(scur, 3, 8);
        int s4 = __shfl(scur, 4, 8), s5 = __shfl(scur, 5, 8);
        int s6 = __shfl(scur, 6, 8), s7 = __shfl(scur, 7, 8);
        H4 v0, v1, v2, v3, v4, v5, v6, v7;
        v0.u = gin[(size_t)s0 * 8 + q];
        v1.u = gin[(size_t)s1 * 8 + q];
        v2.u = gin[(size_t)s2 * 8 + q];
        v3.u = gin[(size_t)s3 * 8 + q];
        v4.u = gin[(size_t)s4 * 8 + q];
        v5.u = gin[(size_t)s5 * 8 + q];
        v6.u = gin[(size_t)s6 * 8 + q];
        v7.u = gin[(size_t)s7 * 8 + q];
        b0l = __hadd2(b0l, v0.h[0]); b0h = __hadd2(b0h, v0.h[1]);
        b1l = __hadd2(b1l, v1.h[0]); b1h = __hadd2(b1h, v1.h[1]);
        b2l = __hadd2(b2l, v2.h[0]); b2h = __hadd2(b2h, v2.h[1]);
        b3l = __hadd2(b3l, v3.h[0]); b3h = __hadd2(b3h, v3.h[1]);
        b0l = __hadd2(b0l, v4.h[0]); b0h = __hadd2(b0h, v4.h[1]);
        b1l = __hadd2(b1l, v5.h[0]); b1h = __hadd2(b1h, v5.h[1]);
        b2l = __hadd2(b2l, v6.h[0]); b2h = __hadd2(b2h, v6.h[1]);
        b3l = __hadd2(b3l, v7.h[0]); b3h = __hadd2(b3h, v7.h[1]);
        if (r & 1) {  // wave-uniform flush every 2 rounds (max 16 fp16 adds)
            float2 t;
            t = __half22float2(b0l); ax += t.x; ay += t.y;
            t = __half22float2(b0h); az += t.x; aw += t.y;
            t = __half22float2(b1l); ax += t.x; ay += t.y;
            t = __half22float2(b1h); az += t.x; aw += t.y;
            t = __half22float2(b2l); ax += t.x; ay += t.y;
            t = __half22float2(b2h); az += t.x; aw += t.y;
            t = __half22float2(b3l); ax += t.x; ay += t.y;
            t = __half22float2(b3h); az += t.x; aw += t.y;
            b0l = __floats2half2_rn(0.f, 0.f); b0h = b0l;
            b1l = b0l; b1h = b0l;
            b2l = b0l; b2h = b0l;
            b3l = b0l; b3h = b0l;
        }
        scur = snext;
    }
    {   // final flush (covers trailing odd round; zeros if already flushed)
        float2 t;
        t = __half22float2(b0l); ax += t.x; ay += t.y;
        t = __half22float2(b0h); az += t.x; aw += t.y;
        t = __half22float2(b1l); ax += t.x; ay += t.y;
        t = __half22float2(b1h); az += t.x; aw += t.y;
        t = __half22float2(b2l); ax += t.x; ay += t.y;
        t = __half22float2(b2h); az += t.x; aw += t.y;
        t = __half22float2(b3l); ax += t.x; ay += t.y;
        t = __half22float2(b3h); az += t.x; aw += t.y;
    }
    float2 g0lo = __half22float2(g0v.h[0]);
    float2 g0hi = __half22float2(g0v.h[1]);
    float rx = w * ax + 0.1f * g0lo.x;
    float ry = w * ay + 0.1f * g0lo.y;
    float rz = w * az + 0.1f * g0hi.x;
    float rw = w * aw + 0.1f * g0hi.y;
    H4 o;
    o.h[0] = __floats2half2_rn(rx, ry);
    o.h[1] = __floats2half2_rn(rz, rw);
    gout[gid] = o.u;
}

// ---------- per-(node,feature) MLP, fused with g->h and h->g conversions ----------
// Covers phantom node n: writes zero (mlp(0) != 0, so explicit).

__global__ __launch_bounds__(256) void mlp_kernel(
    const __half* __restrict__ gin, __half* __restrict__ gout,
    const float* __restrict__ rs, const float* __restrict__ sq,
    const float* __restrict__ emb,   // [32][6]
    const float* __restrict__ W1,    // [7][9] row-major
    const float* __restrict__ b1,    // [9]
    const float* __restrict__ W2,    // [9]
    const float* __restrict__ b2,    // [1]
    int n) {
    __shared__ float c[32][9];
    __shared__ float w0[9], w2[9];
    __shared__ float b2s;
    int tid = threadIdx.x;
    for (int i = tid; i < 288; i += blockDim.x) {
        int f = i / 9, jj = i % 9;
        float acc = b1[jj];
#pragma unroll
        for (int k = 0; k < 6; ++k) acc += emb[f * 6 + k] * W1[(1 + k) * 9 + jj];
        c[f][jj] = acc;
    }
    if (tid < 9) { w0[tid] = W1[tid]; w2[tid] = W2[tid]; }
    if (tid == 0) b2s = b2[0];
    __syncthreads();
    int gid = blockIdx.x * blockDim.x + tid;
    int node = gid >> 5;
    if (node > n) return;
    if (node == n) { gout[gid] = __float2half_rn(0.f); return; }
    int f = gid & 31;
    float xv = __half2float(gin[gid]) * sq[node];
    float acc = b2s;
#pragma unroll
    for (int jj = 0; jj < 9; ++jj)
        acc += fmaxf(xv * w0[jj] + c[f][jj], 0.0f) * w2[jj];
    gout[gid] = __float2half_rn(acc * rs[node]);
}

// ---------- output projection (fused g->h): out = (sq .* g) @ Wout + bout ----------

__global__ __launch_bounds__(256) void out_kernel(
    const __half* __restrict__ g, const float* __restrict__ sq,
    const float* __restrict__ Wout, const float* __restrict__ bout,
    float* __restrict__ out, int n) {
    __shared__ float w[32 * 16];
    __shared__ float bo[16];
    int tid = threadIdx.x;
    for (int i = tid; i < 512; i += blockDim.x) w[i] = Wout[i];
    if (tid < 16) bo[tid] = bout[tid];
    __syncthreads();
    int gid = blockIdx.x * blockDim.x + tid;
    int node = gid >> 4;
    int cls = gid & 15;
    if (node >= n) return;
    const __half* gr = g + (size_t)node * 32;
    float acc = 0.0f;
#pragma unroll
    for (int f = 0; f < 32; ++f) acc += __half2float(gr[f]) * w[f * 16 + cls];
    out[gid] = acc * sq[node] + bo[cls];
}

extern "C" void kernel_launch(void* const* d_in, const int* in_sizes, int n_in,
                              void* d_out, int out_size, void* d_ws, size_t ws_size,
                              hipStream_t stream) {
    const float* x    = (const float*)d_in[0];
    const int* edges  = (const int*)d_in[1];
    const float* emb  = (const float*)d_in[2];
    const float* W1   = (const float*)d_in[3];
    const float* b1   = (const float*)d_in[4];
    const float* W2   = (const float*)d_in[5];
    const float* b2   = (const float*)d_in[6];
    const float* Wout = (const float*)d_in[7];
    const float* bout = (const float*)d_in[8];
    float* out        = (float*)d_out;

    const int N = in_sizes[0] / 32;
    const int E = in_sizes[1] / 2;

    size_t off = 0;
    auto walloc = [&](size_t bytes) {
        void* p = (char*)d_ws + off;
        off += (bytes + 255) & ~(size_t)255;
        return p;
    };
    // all per-node arrays sized N+1 for the phantom (dummy) node N
    int*     deg   = (int*)    walloc((size_t)(N + 1) * 4);
    float*   rs    = (float*)  walloc((size_t)(N + 1) * 4);
    float*   sq    = (float*)  walloc((size_t)(N + 1) * 4);
    float*   wdeg  = (float*)  walloc((size_t)(N + 1) * 4);
    int*     ell   = (int*)    walloc((size_t)(N + 1) * ELL_CAP * 4 + 256);
    __half*  g0buf = (__half*) walloc((size_t)(N + 1) * 32 * 2);
    __half*  bufA  = (__half*) walloc((size_t)(N + 1) * 32 * 2);
    __half*  bufB  = (__half*) walloc((size_t)(N + 1) * 32 * 2);

    hipMemsetAsync(deg, 0, (size_t)(N + 1) * 4, stream);
    // XCD-affinity ELL build: one dispatch, dst slice = blockIdx & 7
    {
        int slice_sz = (N + NSLICE - 1) / NSLICE;
        int chunks = (E + EPB - 1) / EPB;
        ell_fill<<<chunks * NSLICE, 256, 0, stream>>>(edges, deg, ell, E, N, slice_sz);
    }
    nodeconst_kernel<<<(N + 1 + 255) / 256, 256, 0, stream>>>(deg, rs, sq, wdeg, ell, N);

    const int conv_blocks = ((N + 1) * 8 + 255) / 256;
    const int elem_blocks = ((N + 1) * 32 + 255) / 256;
    const int pair_blocks = ((N + 1) * 16 + 255) / 256;

    prescale_kernel<<<pair_blocks, 256, 0, stream>>>((const float2*)x, rs,
                                                     (__half2*)g0buf, N);

    // diffuse #1 in g-space (g0 = g0buf); 10 iters ends in bufB
    {
        const uint2* gin = (const uint2*)g0buf;
        for (int it = 0; it < 10; ++it) {
            uint2* go = (uint2*)((it & 1) ? bufB : bufA);
            conv_kernel<<<conv_blocks, 256, 0, stream>>>(gin, (const uint2*)g0buf, go,
                                                         deg, ell, wdeg, N);
            gin = go;
        }
    }
    // MLP (g->h, mlp, h->g): bufB -> g0buf (becomes g0 of diffuse #2)
    mlp_kernel<<<elem_blocks, 256, 0, stream>>>(bufB, g0buf, rs, sq, emb, W1, b1, W2, b2, N);

    // diffuse #2 in g-space (g0 = g0buf); ends in bufB
    {
        const uint2* gin = (const uint2*)g0buf;
        for (int it = 0; it < 10; ++it) {
            uint2* go = (uint2*)((it & 1) ? bufB : bufA);
            conv_kernel<<<conv_blocks, 256, 0, stream>>>(gin, (const uint2*)g0buf, go,
                                                         deg, ell, wdeg, N);
            gin = go;
        }
    }
    // out = (sq .* bufB) @ Wout + bout
    out_kernel<<<(N * 16 + 255) / 256, 256, 0, stream>>>(bufB, sq, Wout, bout, out, N);
}